// Round 1
// baseline (694.854 us; speedup 1.0000x reference)
//
#include <hip/hip_runtime.h>
#include <math.h>

// Problem constants (from reference setup_inputs):
//   B=32 rows, A=2048 actions, D2=2048 (two heads of D=1024), TOP_K=5, fp32.
// Roofline: a_embeds_target = 512 MB read >> everything else -> HBM-bound,
// ~81 us at 6.3 TB/s achievable.
#define BATCH 32
#define NACT  2048
#define DIM2  2048   // 2*D
#define TOPK  5

// ---------------------------------------------------------------------------
// Kernel 1: logits[h][b][a] = dot(s_embed[b, h*D:(h+1)*D], a_emb[b, a, h*D:(h+1)*D])
// One 64-lane wave per action. Lane l owns columns l*4 + 256*i (i=0..7) as
// float4; s_embed fragment kept in registers (32 VGPRs), a_emb streamed with
// global_load_dwordx4 (1 KB per wave-instruction, fully coalesced).
// ---------------------------------------------------------------------------
#define ACTIONS_PER_BLOCK 32   // 4 waves x 8 actions

__global__ __launch_bounds__(256) void logits_kernel(
    const float* __restrict__ s_embed,   // [B, DIM2]
    const float* __restrict__ a_emb,     // [B, A, DIM2]
    float* __restrict__ logits)          // [2, B, A] in workspace
{
    const int tile  = blockIdx.x;                    // B * (A/APB) tiles
    const int b     = tile / (NACT / ACTIONS_PER_BLOCK);
    const int a0    = (tile % (NACT / ACTIONS_PER_BLOCK)) * ACTIONS_PER_BLOCK;
    const int wave  = threadIdx.x >> 6;
    const int lane  = threadIdx.x & 63;

    // s_embed[b] fragment for this lane: 8 x float4 = 32 floats.
    float4 sreg[8];
    const float* srow = s_embed + (size_t)b * DIM2 + lane * 4;
    #pragma unroll
    for (int i = 0; i < 8; ++i)
        sreg[i] = *(const float4*)(srow + 256 * i);

    const int APW = ACTIONS_PER_BLOCK / 4;           // actions per wave = 8
    for (int j = 0; j < APW; ++j) {
        const int a = a0 + wave * APW + j;
        const float* p = a_emb + ((size_t)b * NACT + a) * DIM2 + lane * 4;
        float d1 = 0.f, d2 = 0.f;
        #pragma unroll
        for (int i = 0; i < 4; ++i) {                // head 1: cols [0,1024)
            float4 v = *(const float4*)(p + 256 * i);
            d1 += v.x * sreg[i].x + v.y * sreg[i].y + v.z * sreg[i].z + v.w * sreg[i].w;
        }
        #pragma unroll
        for (int i = 4; i < 8; ++i) {                // head 2: cols [1024,2048)
            float4 v = *(const float4*)(p + 256 * i);
            d2 += v.x * sreg[i].x + v.y * sreg[i].y + v.z * sreg[i].z + v.w * sreg[i].w;
        }
        // 64-lane butterfly reduction
        #pragma unroll
        for (int off = 32; off >= 1; off >>= 1) {
            d1 += __shfl_xor(d1, off, 64);
            d2 += __shfl_xor(d2, off, 64);
        }
        if (lane == 0) {
            logits[(size_t)b * NACT + a]                         = d1;
            logits[(size_t)BATCH * NACT + (size_t)b * NACT + a]  = d2;
        }
    }
}

// ---------------------------------------------------------------------------
// Kernel 2: per (head, row): 5x sequential block-argmax (tie -> lowest index,
// matching jax.lax.top_k), then masked logsumexp with UNMASKED-max stabilizer:
//   v = alpha * (s + log(max(sum_i avail ? exp(x_i - s) : 0, 1e-10)))
// with x = logits/alpha, s = max(x)  ==>  v = maxlogit + alpha*log(max(sum,eps))
// where sum uses exp((logit - maxlogit)/alpha). Only top-5 indices contribute.
// ---------------------------------------------------------------------------
__global__ __launch_bounds__(256) void topk_lse_kernel(
    const float* __restrict__ logits,   // [2, B, A]
    const int* __restrict__ avail,      // [B, A] (bool as int32)
    const float* __restrict__ alpha_p,  // [1]
    float* __restrict__ out)            // [2*B]: v1 then v2
{
    __shared__ float xs[NACT];
    __shared__ float sval[256];
    __shared__ int   sidx[256];
    __shared__ float smax, ssum;

    const int h = blockIdx.x / BATCH;
    const int b = blockIdx.x % BATCH;
    const int t = threadIdx.x;

    const float* row = logits + ((size_t)h * BATCH + b) * NACT;
    for (int i = t; i < NACT; i += 256) xs[i] = row[i];
    if (t == 0) ssum = 0.f;
    __syncthreads();

    const float alpha = alpha_p[0];

    for (int it = 0; it < TOPK; ++it) {
        // per-thread argmax over strided slice (first hit = lowest index)
        float best = -INFINITY; int bi = NACT;
        for (int i = t; i < NACT; i += 256) {
            float v = xs[i];
            if (v > best) { best = v; bi = i; }
        }
        sval[t] = best; sidx[t] = bi;
        __syncthreads();
        // tree reduce, tie-break lowest index
        for (int stride = 128; stride >= 1; stride >>= 1) {
            if (t < stride) {
                float v2 = sval[t + stride]; int i2 = sidx[t + stride];
                if (v2 > sval[t] || (v2 == sval[t] && i2 < sidx[t])) {
                    sval[t] = v2; sidx[t] = i2;
                }
            }
            __syncthreads();
        }
        if (t == 0) {
            float v = sval[0]; int idx = sidx[0];
            if (it == 0) smax = v;                       // unmasked global max
            if (avail[(size_t)b * NACT + idx])
                ssum += expf((v - smax) / alpha);
            xs[idx] = -INFINITY;                         // extract
        }
        __syncthreads();
    }

    if (t == 0) {
        float sum = fmaxf(ssum, 1e-10f);
        out[h * BATCH + b] = smax + alpha * logf(sum);
    }
}

// ---------------------------------------------------------------------------
extern "C" void kernel_launch(void* const* d_in, const int* in_sizes, int n_in,
                              void* d_out, int out_size, void* d_ws, size_t ws_size,
                              hipStream_t stream) {
    const float* s_embed = (const float*)d_in[0];   // [32, 2048] fp32
    const float* a_emb   = (const float*)d_in[1];   // [32, 2048, 2048] fp32
    const int*   avail   = (const int*)d_in[2];     // [32, 2048] bool->int32
    const float* alpha   = (const float*)d_in[3];   // [1] fp32
    float*       out     = (float*)d_out;           // [64] fp32 (v1 ++ v2)
    float*       logits  = (float*)d_ws;            // [2, 32, 2048] = 512 KB

    logits_kernel<<<BATCH * (NACT / ACTIONS_PER_BLOCK), 256, 0, stream>>>(
        s_embed, a_emb, logits);
    topk_lse_kernel<<<2 * BATCH, 256, 0, stream>>>(logits, avail, alpha, out);
}

// Round 2
// 683.615 us; speedup vs baseline: 1.0164x; 1.0164x over previous
//
#include <hip/hip_runtime.h>
#include <math.h>

// Problem: B=32, A=2048, D2=2048 (two heads of D=1024), TOP_K=5, fp32.
// a_embeds_target = 512 MB read per call >> all else -> HBM-bound.
// Roofline: 512 MB / 6.3 TB/s ~= 81 us for kernel 1; kernel 2 reads 512 KB.
// NOTE (R1 post-mortem): bench dur_us includes ~500 us of harness reset
// (2 GB d_ws 0xAA fill ~333 us + 512 MB d_in restore ~160 us per iteration);
// our controllable share is kernel time only.
#define BATCH 32
#define NACT  2048
#define DIM2  2048   // 2*D
#define TOPK  5
#define ACTIONS_PER_BLOCK 32   // 4 waves x 8 actions
#define APW   8                // actions per wave

// ---------------------------------------------------------------------------
// Kernel 1: logits[h][b][a] = dot(s[b, hD:(h+1)D], a_emb[b, a, hD:(h+1)D]).
// One wave per 8 actions. Lane l owns columns l*4 + 256*i (i=0..7) as float4.
// Load+FMA loops are fully unrolled with NO cross-lane ops inside -> pure
// global_load_dwordx4 stream (1 KB/wave-instr). All 16 butterfly reductions
// deferred to the end as independent chains (ILP hides ds_swizzle latency).
// ---------------------------------------------------------------------------
__global__ __launch_bounds__(256) void logits_kernel(
    const float* __restrict__ s_embed,   // [B, DIM2]
    const float* __restrict__ a_emb,     // [B, A, DIM2]
    float* __restrict__ logits)          // [2, B, A] in workspace
{
    const int tile  = blockIdx.x;                 // 32*64 tiles
    const int b     = tile >> 6;                  // NACT/ACTIONS_PER_BLOCK=64
    const int a0    = (tile & 63) * ACTIONS_PER_BLOCK;
    const int wave  = threadIdx.x >> 6;
    const int lane  = threadIdx.x & 63;

    // s_embed[b] fragment for this lane: 8 x float4 = 32 floats in VGPRs.
    float4 sreg[8];
    const float* srow = s_embed + (size_t)b * DIM2 + lane * 4;
    #pragma unroll
    for (int i = 0; i < 8; ++i)
        sreg[i] = *(const float4*)(srow + 256 * i);

    const int abase = a0 + wave * APW;
    const float* pbase = a_emb + ((size_t)b * NACT + abase) * DIM2 + lane * 4;

    float acc1[APW], acc2[APW];
    #pragma unroll
    for (int j = 0; j < APW; ++j) {
        const float* p = pbase + (size_t)j * DIM2;
        float d1 = 0.f, d2 = 0.f;
        #pragma unroll
        for (int i = 0; i < 4; ++i) {             // head 1: cols [0,1024)
            float4 v = *(const float4*)(p + 256 * i);
            d1 += v.x * sreg[i].x + v.y * sreg[i].y + v.z * sreg[i].z + v.w * sreg[i].w;
        }
        #pragma unroll
        for (int i = 4; i < 8; ++i) {             // head 2: cols [1024,2048)
            float4 v = *(const float4*)(p + 256 * i);
            d2 += v.x * sreg[i].x + v.y * sreg[i].y + v.z * sreg[i].z + v.w * sreg[i].w;
        }
        acc1[j] = d1;
        acc2[j] = d2;
    }

    // Batched butterfly reductions: 16 independent chains.
    #pragma unroll
    for (int off = 32; off >= 1; off >>= 1) {
        #pragma unroll
        for (int j = 0; j < APW; ++j) {
            acc1[j] += __shfl_xor(acc1[j], off, 64);
            acc2[j] += __shfl_xor(acc2[j], off, 64);
        }
    }

    if (lane == 0) {
        float* o1 = logits + (size_t)b * NACT + abase;
        float* o2 = o1 + (size_t)BATCH * NACT;
        #pragma unroll
        for (int j = 0; j < APW; ++j) { o1[j] = acc1[j]; o2[j] = acc2[j]; }
    }
}

// ---------------------------------------------------------------------------
// Kernel 2: one wave per (head,row). Row (2048 floats) lives in registers
// (32/lane, strided: lane l holds elements 64k+l). 5x shfl-argmax with
// lowest-index tie-break (matches jax.lax.top_k), then masked LSE with
// UNMASKED-max stabilizer and eps clamp:
//   out = maxlogit + alpha * log(max(sum_{top5 & avail} exp((x-maxlogit)/alpha), 1e-10))
// No LDS, no __syncthreads.
// ---------------------------------------------------------------------------
__global__ __launch_bounds__(256) void topk_lse_kernel(
    const float* __restrict__ logits,   // [2, B, A]
    const int* __restrict__ avail,      // [B, A] (bool as int32)
    const float* __restrict__ alpha_p,  // [1]
    float* __restrict__ out)            // [2*B]: v1 then v2
{
    const int row  = blockIdx.x * 4 + (threadIdx.x >> 6);  // 0..63 = h*32+b
    const int lane = threadIdx.x & 63;
    const int b    = row & 31;

    const float* x = logits + (size_t)row * NACT;
    float v[32];
    #pragma unroll
    for (int k = 0; k < 32; ++k) v[k] = x[k * 64 + lane];  // coalesced

    const float alpha = alpha_p[0];
    float smax = 0.f, ssum = 0.f;

    for (int it = 0; it < TOPK; ++it) {
        // lane-local argmax; k ascending + strict '>' keeps lowest index
        float best = -INFINITY; int bi = 1 << 30;
        #pragma unroll
        for (int k = 0; k < 32; ++k) {
            float val = v[k];
            if (val > best) { best = val; bi = k * 64 + lane; }
        }
        // wave argmax, tie -> lowest linear index
        #pragma unroll
        for (int off = 32; off >= 1; off >>= 1) {
            float v2 = __shfl_xor(best, off, 64);
            int   i2 = __shfl_xor(bi,   off, 64);
            if (v2 > best || (v2 == best && i2 < bi)) { best = v2; bi = i2; }
        }
        if (it == 0) smax = best;                 // unmasked global max
        if (avail[(size_t)b * NACT + bi])         // broadcast load
            ssum += expf((best - smax) / alpha);
        #pragma unroll
        for (int k = 0; k < 32; ++k)              // extract without dyn-index
            if (k * 64 + lane == bi) v[k] = -INFINITY;
    }

    if (lane == 0)
        out[row] = smax + alpha * logf(fmaxf(ssum, 1e-10f));
}

// ---------------------------------------------------------------------------
extern "C" void kernel_launch(void* const* d_in, const int* in_sizes, int n_in,
                              void* d_out, int out_size, void* d_ws, size_t ws_size,
                              hipStream_t stream) {
    const float* s_embed = (const float*)d_in[0];   // [32, 2048] fp32
    const float* a_emb   = (const float*)d_in[1];   // [32, 2048, 2048] fp32
    const int*   avail   = (const int*)d_in[2];     // [32, 2048] bool->int32
    const float* alpha   = (const float*)d_in[3];   // [1] fp32
    float*       out     = (float*)d_out;           // [64] fp32 (v1 ++ v2)
    float*       logits  = (float*)d_ws;            // [2, 32, 2048] = 512 KB

    logits_kernel<<<BATCH * (NACT / ACTIONS_PER_BLOCK), 256, 0, stream>>>(
        s_embed, a_emb, logits);
    topk_lse_kernel<<<16, 256, 0, stream>>>(logits, avail, alpha, out);
}